// Round 7
// baseline (2123.041 us; speedup 1.0000x reference)
//
#include <hip/hip_runtime.h>

#define BB 8
#define TT 2048
#define CC 32
#define HH 2048
#define QB 128
#define HB 128
#define SB 64
#define SCALE 0.17677669529663687f  // 1/sqrt(32)

typedef _Float16 f16;
typedef f16 f16x8 __attribute__((ext_vector_type(8)));
typedef float f32x4 __attribute__((ext_vector_type(4)));

// ---------------- K0: M = Wq @ Wk^T  [32 x 32] ----------------
__global__ __launch_bounds__(1024) void mk_kernel(const float* __restrict__ Wq,
                                                  const float* __restrict__ Wk,
                                                  float* __restrict__ M) {
    const int c  = threadIdx.x >> 5;
    const int cp = threadIdx.x & 31;
    const float4* a = (const float4*)(Wq + (size_t)c * HH);
    const float4* b = (const float4*)(Wk + (size_t)cp * HH);
    float acc = 0.f;
    for (int i = 0; i < HH / 4; i++) {
        float4 av = a[i], bv = b[i];
        acc += av.x * bv.x + av.y * bv.y + av.z * bv.z + av.w * bv.w;
    }
    M[c * 32 + cp] = acc;
}

// ---------- K1: v = x@Wv (fp16), y = x@M (fp16), xh = fp16(x) ----------
__global__ __launch_bounds__(256) void proj_kernel(
    const float* __restrict__ x, const float* __restrict__ Wv,
    const float* __restrict__ M,
    f16* __restrict__ vh, f16* __restrict__ yh, f16* __restrict__ xh) {
    __shared__ float xs[8][CC];
    const int tid = threadIdx.x;
    const size_t rbase = (size_t)blockIdx.x * 8;
    float xv = x[rbase * CC + tid];
    xs[tid >> 5][tid & 31] = xv;
    xh[rbase * CC + tid] = (f16)xv;
    __syncthreads();
    {   // y = x @ M
        const int r = tid >> 5, cp = tid & 31;
        float acc = 0.f;
        #pragma unroll
        for (int c = 0; c < CC; c++) acc += xs[r][c] * M[c * 32 + cp];
        yh[(rbase + r) * CC + cp] = (f16)acc;
    }
    // v = x @ Wv
    for (int it = 0; it < 8; it++) {
        const int h = tid + it * 256;
        float acc[8] = {0, 0, 0, 0, 0, 0, 0, 0};
        #pragma unroll
        for (int c = 0; c < CC; c++) {
            const float w = Wv[(size_t)c * HH + h];
            #pragma unroll
            for (int r = 0; r < 8; r++) acc[r] += xs[r][c] * w;
        }
        #pragma unroll
        for (int r = 0; r < 8; r++) vh[(rbase + r) * HH + h] = (f16)acc[r];
    }
}

// ---------------- K2: fused scores + softmax + PV ----------------
// Block: 256 threads (4 waves, 2x2 wave grid), output tile QB x HB.
__global__ __launch_bounds__(256) void attn_kernel(
    const f16* __restrict__ xh, const f16* __restrict__ yh,
    const f16* __restrict__ vh, float* __restrict__ out) {
    // XCD-bijective swizzle: each XCD owns one batch; ht outer, qt inner,
    // so same-XCD neighbors share v column panels (0.5 MB -> L2 resident).
    const int bid = blockIdx.x;                 // 0..2047
    const int sw  = (bid & 7) * 256 + (bid >> 3);
    const int b   = sw >> 8;
    const int ht  = (sw >> 4) & 15;
    const int qt  = sw & 15;

    const int tid = threadIdx.x;
    const int wave = tid >> 6, lane = tid & 63;
    const int g = lane >> 4, li = lane & 15;
    const int wr = wave >> 1, wc = wave & 1;
    const int qbase = qt * QB, hbase = ht * HB;

    __shared__ f16 yq[QB][40];   // stride 80B (20 banks): 2-way max
    __shared__ f16 xs[SB][40];
    __shared__ f16 vt[HB][72];   // vt[h][s], col XOR-swizzled by ((h>>3)&3)<<4
    __shared__ f16 ps[QB][72];   // ps[q][s], col XOR-swizzled by ((q>>2)&3)<<4

    const f16* xp = xh + (size_t)b * TT * CC;
    const f16* yp = yh + (size_t)b * TT * CC;
    const f16* vp = vh + (size_t)b * TT * HH;

    #pragma unroll
    for (int i = 0; i < 2; i++) {
        const int idx = tid + i * 256;
        const int rr = idx >> 2, c8 = (idx & 3) * 8;
        *(f16x8*)&yq[rr][c8] = *(const f16x8*)&yp[(size_t)(qbase + rr) * CC + c8];
    }

    f32x4 o[4][4] = {};
    float m_[4][4], l_[4][4];
    #pragma unroll
    for (int a1 = 0; a1 < 4; a1++)
        #pragma unroll
        for (int a2 = 0; a2 < 4; a2++) { m_[a1][a2] = -1e30f; l_[a1][a2] = 0.f; }

    const int qrow0 = qbase + wr * 64;
    const int nst = 2 * qt + 2;

    for (int st = 0; st < nst; st++) {
        const int sbase = st * SB;
        __syncthreads();
        {   // stage xs [64][32]
            const int rr = tid >> 2, c8 = (tid & 3) * 8;
            *(f16x8*)&xs[rr][c8] = *(const f16x8*)&xp[(size_t)(sbase + rr) * CC + c8];
        }
        // stage vt = v^T with XOR swizzle (2-way conflicts on write)
        #pragma unroll
        for (int i = 0; i < 4; i++) {
            const int idx = tid + i * 256;
            const int s_r = ((idx >> 8) << 4) | (idx & 15);
            const int h8  = ((idx >> 4) & 15) * 8;
            const f16x8 vv = *(const f16x8*)&vp[(size_t)(sbase + s_r) * HH + hbase + h8];
            const int sw8 = ((h8 >> 3) & 3) << 4;
            #pragma unroll
            for (int j = 0; j < 8; j++) vt[h8 + j][s_r ^ sw8] = vv[j];
        }
        __syncthreads();

        const bool diag = (sbase + SB - 1) > qrow0;

        f16x8 bf[4];
        #pragma unroll
        for (int sf = 0; sf < 4; sf++) bf[sf] = *(const f16x8*)&xs[sf * 16 + li][g * 8];

        #pragma unroll
        for (int rf = 0; rf < 4; rf++) {
            const f16x8 af = *(const f16x8*)&yq[wr * 64 + rf * 16 + li][g * 8];
            f32x4 sc[4];
            #pragma unroll
            for (int sf = 0; sf < 4; sf++) {
                f32x4 z = {};
                sc[sf] = __builtin_amdgcn_mfma_f32_16x16x32_f16(af, bf[sf], z, 0, 0, 0);
            }
            #pragma unroll
            for (int reg = 0; reg < 4; reg++) {
                const int row = qrow0 + rf * 16 + g * 4 + reg;
                float sv[4], tmax = -1e30f;
                #pragma unroll
                for (int sf = 0; sf < 4; sf++) {
                    float s = sc[sf][reg] * SCALE;
                    if (diag && (sbase + sf * 16 + li) > row) s = -1e30f;
                    sv[sf] = s;
                    tmax = fmaxf(tmax, s);
                }
                #pragma unroll
                for (int off = 1; off < 16; off <<= 1)
                    tmax = fmaxf(tmax, __shfl_xor(tmax, off, 64));
                const float mo = m_[rf][reg];
                const float mn = fmaxf(mo, tmax);
                float p[4], psum = 0.f;
                #pragma unroll
                for (int sf = 0; sf < 4; sf++) { p[sf] = __expf(sv[sf] - mn); psum += p[sf]; }
                #pragma unroll
                for (int off = 1; off < 16; off <<= 1)
                    psum += __shfl_xor(psum, off, 64);
                if (mn > mo) {   // defer-rescale: skip when max unchanged
                    const float al = __expf(mo - mn);
                    l_[rf][reg] = l_[rf][reg] * al + psum;
                    m_[rf][reg] = mn;
                    #pragma unroll
                    for (int hf = 0; hf < 4; hf++) o[rf][hf][reg] *= al;
                } else {
                    l_[rf][reg] += psum;
                }
                if (wc == 0) {
                    const int prow = wr * 64 + rf * 16 + g * 4 + reg;
                    const int swp = (g & 3) << 4;   // == ((prow>>2)&3)<<4
                    #pragma unroll
                    for (int sf = 0; sf < 4; sf++)
                        ps[prow][(sf * 16 + li) ^ swp] = (f16)p[sf];
                }
            }
        }
        __syncthreads();
        // PV: o += P @ V   (A = ps rows q, B = vt rows h, k = s)
        #pragma unroll
        for (int kk = 0; kk < 2; kk++) {
            f16x8 pa[4];
            #pragma unroll
            for (int rf = 0; rf < 4; rf++) {
                const int prow = wr * 64 + rf * 16 + li;
                const int swp = ((li >> 2) & 3) << 4;
                pa[rf] = *(const f16x8*)&ps[prow][(kk * 32 + g * 8) ^ swp];
            }
            #pragma unroll
            for (int hf = 0; hf < 4; hf++) {
                const int vrow = wc * 64 + hf * 16 + li;
                const int swv = ((vrow >> 3) & 3) << 4;
                const f16x8 vb = *(const f16x8*)&vt[vrow][(kk * 32 + g * 8) ^ swv];
                #pragma unroll
                for (int rf = 0; rf < 4; rf++)
                    o[rf][hf] = __builtin_amdgcn_mfma_f32_16x16x32_f16(pa[rf], vb, o[rf][hf], 0, 0, 0);
            }
        }
    }

    float* op = out + (size_t)b * TT * HH;
    #pragma unroll
    for (int rf = 0; rf < 4; rf++) {
        #pragma unroll
        for (int reg = 0; reg < 4; reg++) {
            const int row = qrow0 + rf * 16 + g * 4 + reg;
            const float inv = 1.f / l_[rf][reg];
            #pragma unroll
            for (int hf = 0; hf < 4; hf++)
                op[(size_t)row * HH + hbase + wc * 64 + hf * 16 + li] = o[rf][hf][reg] * inv;
        }
    }
}

extern "C" void kernel_launch(void* const* d_in, const int* in_sizes, int n_in,
                              void* d_out, int out_size, void* d_ws, size_t ws_size,
                              hipStream_t stream) {
    const float* x  = (const float*)d_in[0];
    const float* Wk = (const float*)d_in[1];
    const float* Wq = (const float*)d_in[2];
    const float* Wv = (const float*)d_in[3];
    float* out = (float*)d_out;

    float* Mp = (float*)d_ws;                          // 32x32 fp32 (4 KB slot)
    f16* xh = (f16*)((char*)d_ws + 4096);              // B*T*32 fp16 (1 MB)
    f16* yh = xh + (size_t)BB * TT * CC;               // B*T*32 fp16 (1 MB)
    f16* vh = yh + (size_t)BB * TT * CC;               // B*T*H fp16 (67 MB)

    mk_kernel<<<1, 1024, 0, stream>>>(Wq, Wk, Mp);
    proj_kernel<<<(BB * TT) / 8, 256, 0, stream>>>(x, Wv, Mp, vh, yh, xh);
    attn_kernel<<<BB * (TT / QB) * (HH / HB), 256, 0, stream>>>(xh, yh, vh, out);
}

// Round 12
// 484.071 us; speedup vs baseline: 4.3858x; 4.3858x over previous
//
#include <hip/hip_runtime.h>

#define BB 8
#define TT 2048
#define CC 32
#define HH 2048
#define QB 128
#define HB 128
#define SCALE 0.17677669529663687f        // 1/sqrt(32)
#define K2E   0.25503255741f              // SCALE * log2(e)

typedef _Float16 f16;
typedef f16 f16x8 __attribute__((ext_vector_type(8)));
typedef f16 f16x4 __attribute__((ext_vector_type(4)));
typedef float f32x4 __attribute__((ext_vector_type(4)));

// ---------------- K0: M = Wq @ Wk^T  [32 x 32] ----------------
// grid 256 x 256: one wave per output element, 4 outputs/block
__global__ __launch_bounds__(256) void mk_kernel(const float* __restrict__ Wq,
                                                 const float* __restrict__ Wk,
                                                 float* __restrict__ M) {
    const int o = blockIdx.x * 4 + (threadIdx.x >> 6);
    const int lane = threadIdx.x & 63;
    const int c = o >> 5, cp = o & 31;
    const float4* a = (const float4*)(Wq + (size_t)c * HH);
    const float4* b = (const float4*)(Wk + (size_t)cp * HH);
    float acc = 0.f;
    #pragma unroll
    for (int i = 0; i < 8; i++) {
        float4 av = a[lane + i * 64], bv = b[lane + i * 64];
        acc += av.x * bv.x + av.y * bv.y + av.z * bv.z + av.w * bv.w;
    }
    #pragma unroll
    for (int off = 1; off < 64; off <<= 1) acc += __shfl_xor(acc, off, 64);
    if (lane == 0) M[c * 32 + cp] = acc;
}

// ---------- K1: xh = f16(x), yh = f16(x @ M) ----------
__global__ __launch_bounds__(256) void proj2_kernel(const float* __restrict__ x,
                                                    const float* __restrict__ M,
                                                    f16* __restrict__ yh,
                                                    f16* __restrict__ xh) {
    __shared__ float xs2[32][33];
    const int tid = threadIdx.x;
    const size_t rbase = (size_t)blockIdx.x * 32;
    const int r = tid >> 3, c4 = (tid & 7) * 4;
    float4 xv = *(const float4*)&x[(rbase + r) * CC + c4];
    xs2[r][c4 + 0] = xv.x; xs2[r][c4 + 1] = xv.y;
    xs2[r][c4 + 2] = xv.z; xs2[r][c4 + 3] = xv.w;
    f16x4 xf = {(f16)xv.x, (f16)xv.y, (f16)xv.z, (f16)xv.w};
    *(f16x4*)&xh[(rbase + r) * CC + c4] = xf;
    __syncthreads();
    float a0 = 0.f, a1 = 0.f, a2 = 0.f, a3 = 0.f;
    #pragma unroll
    for (int c = 0; c < 32; c++) {
        const float xr = xs2[r][c];
        const float4 mv = *(const float4*)&M[c * 32 + c4];
        a0 += xr * mv.x; a1 += xr * mv.y; a2 += xr * mv.z; a3 += xr * mv.w;
    }
    f16x4 yf = {(f16)a0, (f16)a1, (f16)a2, (f16)a3};
    *(f16x4*)&yh[(rbase + r) * CC + c4] = yf;
}

// ---------------- K2: fused scores + softmax + V-projection + PV ----------------
// 256 threads (4 waves, wr x wc = 2x2). Two-pass exact-max softmax.
// Swapped QK: D[s][q] = mfma(x_s, y_q)  -> p is q-in-lane, s packed in regs.
// V computed in-kernel: D[s][h] = mfma(x_s, Wv^T_h). Pipelined: PV(st) uses ps/vt of st-1.
__global__ __launch_bounds__(256, 3) void attn_kernel(
    const f16* __restrict__ xh, const f16* __restrict__ yh,
    const float* __restrict__ Wv, float* __restrict__ out)
{
    const int bid = blockIdx.x;                  // 0..2047
    const int qt  = 15 - (bid >> 7);             // long blocks launch first
    const int b   = (bid >> 4) & 7;
    const int ht  = bid & 15;
    const int tid = threadIdx.x;
    const int lane = tid & 63, wave = tid >> 6;
    const int g = lane >> 4, li = lane & 15;
    const int wr = wave >> 1, wc = wave & 1;
    const int qbase = qt * QB, hbase = ht * HB;
    const int qrow0 = qbase + wr * 64;
    const int nst = 2 * qt + 2;

    __shared__ __align__(16) f16 smem[64 * 40 + 128 * 72 + 128 * 72];  // 44032 B w/ mh,lh
    f16 (*xs)[40] = (f16(*)[40])smem;
    f16 (*vt)[72] = (f16(*)[72])(smem + 64 * 40);
    f16 (*ps)[72] = (f16(*)[72])(smem + 64 * 40 + 128 * 72);
    __shared__ float mh[2][128];
    __shared__ float lh[2][128];

    const f16* xp = xh + (size_t)b * TT * CC;
    const f16* yp = yh + (size_t)b * TT * CC;

    // y fragments (B-operand of swapped QK): rows q
    f16x8 af[4];
    #pragma unroll
    for (int rf = 0; rf < 4; rf++)
        af[rf] = *(const f16x8*)&yp[(size_t)(qbase + wr * 64 + rf * 16 + li) * CC + g * 8];

    // Wv^T fragments (B-operand of V-compute): wv[hf][j] = Wv[g*8+j][h]
    f16x8 wv[4];
    #pragma unroll
    for (int hf = 0; hf < 4; hf++) {
        #pragma unroll
        for (int j = 0; j < 8; j++)
            wv[hf][j] = (f16)Wv[(size_t)(g * 8 + j) * HH + hbase + wc * 64 + hf * 16 + li];
    }

    const int rr = tid >> 2, c8 = (tid & 3) * 8;

    // ---------------- pass 1: exact row max (lane-local, no per-step shuffles) ----------------
    float mp[4] = {-3e38f, -3e38f, -3e38f, -3e38f};
    f16 (*x4)[64][40] = (f16(*)[64][40])smem;    // alias xs+vt region (4 tiles = 20.5 KB)
    for (int ch = 0; ch * 4 < nst; ch++) {
        __syncthreads();
        #pragma unroll
        for (int j = 0; j < 4; j++) {
            const int st = ch * 4 + j;
            if (st < nst)
                *(f16x8*)&x4[j][rr][c8] = *(const f16x8*)&xp[(size_t)(st * 64 + rr) * CC + c8];
        }
        __syncthreads();
        #pragma unroll
        for (int j = 0; j < 4; j++) {
            const int st = ch * 4 + j;
            if (st < nst) {
                const int sbase = st * 64;
                const bool diag = (sbase + 63) > qrow0;
                #pragma unroll
                for (int sfi = 0; sfi < 2; sfi++) {
                    const f16x8 xa = *(const f16x8*)&x4[j][(2 * wc + sfi) * 16 + li][g * 8];
                    const int sb2 = sbase + (2 * wc + sfi) * 16 + g * 4;
                    #pragma unroll
                    for (int rf = 0; rf < 4; rf++) {
                        f32x4 z = {};
                        f32x4 sc = __builtin_amdgcn_mfma_f32_16x16x32_f16(xa, af[rf], z, 0, 0, 0);
                        const int qg = qbase + wr * 64 + rf * 16 + li;
                        #pragma unroll
                        for (int reg = 0; reg < 4; reg++) {
                            float v = sc[reg];
                            if (diag && (sb2 + reg) > qg) v = -3e38f;
                            mp[rf] = fmaxf(mp[rf], v);
                        }
                    }
                }
            }
        }
    }
    #pragma unroll
    for (int rf = 0; rf < 4; rf++) {
        mp[rf] = fmaxf(mp[rf], __shfl_xor(mp[rf], 16, 64));
        mp[rf] = fmaxf(mp[rf], __shfl_xor(mp[rf], 32, 64));
    }
    if (g == 0) {
        #pragma unroll
        for (int rf = 0; rf < 4; rf++) mh[wc][wr * 64 + rf * 16 + li] = mp[rf];
    }
    __syncthreads();     // mh visible; all pass-1 x4 reads complete
    float m2[4];
    #pragma unroll
    for (int rf = 0; rf < 4; rf++)
        m2[rf] = fmaxf(mh[0][wr * 64 + rf * 16 + li], mh[1][wr * 64 + rf * 16 + li]) * K2E;

    // ---------------- pass 2: fused softmax + V-compute + PV (pipelined) ----------------
    f16x8 xn = *(const f16x8*)&xp[(size_t)rr * CC + c8];   // x(0)
    *(f16x8*)&xs[rr][c8] = xn;
    __syncthreads();

    f32x4 o[4][4] = {};
    float lp[4] = {0.f, 0.f, 0.f, 0.f};
    f16x4 pf0[4], pf1[4];   // p fragments [rf], sfi = 0/1
    f16x4 vf0[4], vf1[4];   // v fragments [hf], sfw = 0/1

    for (int st = 0; st <= nst; st++) {
        const int sbase = st * 64;
        const bool haveQ = (st < nst);
        if (haveQ) {
            if (st + 1 < nst)
                xn = *(const f16x8*)&xp[(size_t)((st + 1) * 64 + rr) * CC + c8];
            const bool diag = (sbase + 63) > qrow0;
            const f16x8 xa0 = *(const f16x8*)&xs[(2 * wc + 0) * 16 + li][g * 8];
            const f16x8 xa1 = *(const f16x8*)&xs[(2 * wc + 1) * 16 + li][g * 8];
            const f16x8 xw0 = *(const f16x8*)&xs[(2 * wr + 0) * 16 + li][g * 8];
            const f16x8 xw1 = *(const f16x8*)&xs[(2 * wr + 1) * 16 + li][g * 8];
            // QK + exp (fixed m: no max tracking, no rescale, no shuffles)
            #pragma unroll
            for (int sfi = 0; sfi < 2; sfi++) {
                const f16x8 xa = sfi ? xa1 : xa0;
                const int sb2 = sbase + (2 * wc + sfi) * 16 + g * 4;
                #pragma unroll
                for (int rf = 0; rf < 4; rf++) {
                    f32x4 z = {};
                    f32x4 sc = __builtin_amdgcn_mfma_f32_16x16x32_f16(xa, af[rf], z, 0, 0, 0);
                    const int qg = qbase + wr * 64 + rf * 16 + li;
                    f16x4 pv;
                    #pragma unroll
                    for (int reg = 0; reg < 4; reg++) {
                        float e = exp2f(fmaf(sc[reg], K2E, -m2[rf]));
                        if (diag && (sb2 + reg) > qg) e = 0.f;
                        lp[rf] += e;
                        pv[reg] = (f16)e;
                    }
                    if (sfi == 0) pf0[rf] = pv; else pf1[rf] = pv;
                }
            }
            // V-compute: v(st) = x(st) @ Wv  (K=32 MFMA, s-in-reg layout -> packed writes)
            #pragma unroll
            for (int sfw = 0; sfw < 2; sfw++) {
                const f16x8 xw = sfw ? xw1 : xw0;
                #pragma unroll
                for (int hf = 0; hf < 4; hf++) {
                    f32x4 z = {};
                    f32x4 vc = __builtin_amdgcn_mfma_f32_16x16x32_f16(xw, wv[hf], z, 0, 0, 0);
                    f16x4 vv4;
                    #pragma unroll
                    for (int reg = 0; reg < 4; reg++) vv4[reg] = (f16)vc[reg];
                    if (sfw == 0) vf0[hf] = vv4; else vf1[hf] = vv4;
                }
            }
        }
        if (st > 0) {
            // PV: o += P(st-1) @ V(st-1)
            #pragma unroll
            for (int kk = 0; kk < 2; kk++) {
                f16x8 pa[4];
                #pragma unroll
                for (int rf = 0; rf < 4; rf++) {
                    const int prow = wr * 64 + rf * 16 + li;
                    pa[rf] = *(const f16x8*)&ps[prow][(kk * 32 + g * 8) ^ (((prow >> 2) & 3) << 4)];
                }
                #pragma unroll
                for (int hf = 0; hf < 4; hf++) {
                    const int vrow = wc * 64 + hf * 16 + li;
                    const f16x8 vb = *(const f16x8*)&vt[vrow][(kk * 32 + g * 8) ^ (((vrow >> 3) & 3) << 4)];
                    #pragma unroll
                    for (int rf = 0; rf < 4; rf++)
                        o[rf][hf] = __builtin_amdgcn_mfma_f32_16x16x32_f16(pa[rf], vb, o[rf][hf], 0, 0, 0);
                }
            }
        }
        __syncthreads();
        if (haveQ) {
            #pragma unroll
            for (int rf = 0; rf < 4; rf++) {
                const int prow = wr * 64 + rf * 16 + li;
                const int swp = ((prow >> 2) & 3) << 4;
                *(f16x4*)&ps[prow][((2 * wc + 0) * 16 + g * 4) ^ swp] = pf0[rf];
                *(f16x4*)&ps[prow][((2 * wc + 1) * 16 + g * 4) ^ swp] = pf1[rf];
            }
            #pragma unroll
            for (int hf = 0; hf < 4; hf++) {
                const int vrow = wc * 64 + hf * 16 + li;
                const int swv = ((vrow >> 3) & 3) << 4;
                *(f16x4*)&vt[vrow][((2 * wr + 0) * 16 + g * 4) ^ swv] = vf0[hf];
                *(f16x4*)&vt[vrow][((2 * wr + 1) * 16 + g * 4) ^ swv] = vf1[hf];
            }
            if (st + 1 < nst)
                *(f16x8*)&xs[rr][c8] = xn;
            __syncthreads();
        }
    }

    // l reduce (once) + epilogue
    #pragma unroll
    for (int rf = 0; rf < 4; rf++) {
        lp[rf] += __shfl_xor(lp[rf], 16, 64);
        lp[rf] += __shfl_xor(lp[rf], 32, 64);
    }
    if (g == 0) {
        #pragma unroll
        for (int rf = 0; rf < 4; rf++) lh[wc][wr * 64 + rf * 16 + li] = lp[rf];
    }
    __syncthreads();
    float* op = out + (size_t)b * TT * HH;
    #pragma unroll
    for (int rf = 0; rf < 4; rf++) {
        #pragma unroll
        for (int reg = 0; reg < 4; reg++) {
            const int ql = wr * 64 + rf * 16 + g * 4 + reg;
            const float inv = 1.f / (lh[0][ql] + lh[1][ql]);
            #pragma unroll
            for (int hf = 0; hf < 4; hf++)
                op[(size_t)(qbase + ql) * HH + hbase + wc * 64 + hf * 16 + li] = o[rf][hf][reg] * inv;
        }
    }
}

extern "C" void kernel_launch(void* const* d_in, const int* in_sizes, int n_in,
                              void* d_out, int out_size, void* d_ws, size_t ws_size,
                              hipStream_t stream) {
    const float* x  = (const float*)d_in[0];
    const float* Wk = (const float*)d_in[1];
    const float* Wq = (const float*)d_in[2];
    const float* Wv = (const float*)d_in[3];
    float* out = (float*)d_out;

    float* Mp = (float*)d_ws;                        // 32x32 fp32
    f16* xh = (f16*)((char*)d_ws + 4096);            // B*T*32 f16 (1 MB)
    f16* yh = xh + (size_t)BB * TT * CC;             // B*T*32 f16 (1 MB)

    mk_kernel<<<256, 256, 0, stream>>>(Wq, Wk, Mp);
    proj2_kernel<<<(BB * TT) / 32, 256, 0, stream>>>(x, Mp, yh, xh);
    attn_kernel<<<BB * (TT / QB) * (HH / HB), 256, 0, stream>>>(xh, yh, Wv, out);
}

// Round 14
// 432.447 us; speedup vs baseline: 4.9094x; 1.1194x over previous
//
#include <hip/hip_runtime.h>

#define BB 8
#define TT 2048
#define CC 32
#define HH 2048
#define QB 128
#define HB 128
#define K2E   0.25503255741f              // (1/sqrt(32)) * log2(e)

typedef _Float16 f16;
typedef f16 f16x8 __attribute__((ext_vector_type(8)));
typedef f16 f16x4 __attribute__((ext_vector_type(4)));
typedef float f32x4 __attribute__((ext_vector_type(4)));

// ---------------- K0: M = Wq @ Wk^T  [32 x 32] ----------------
__global__ __launch_bounds__(256) void mk_kernel(const float* __restrict__ Wq,
                                                 const float* __restrict__ Wk,
                                                 float* __restrict__ M) {
    const int o = blockIdx.x * 4 + (threadIdx.x >> 6);
    const int lane = threadIdx.x & 63;
    const int c = o >> 5, cp = o & 31;
    const float4* a = (const float4*)(Wq + (size_t)c * HH);
    const float4* b = (const float4*)(Wk + (size_t)cp * HH);
    float acc = 0.f;
    #pragma unroll
    for (int i = 0; i < 8; i++) {
        float4 av = a[lane + i * 64], bv = b[lane + i * 64];
        acc += av.x * bv.x + av.y * bv.y + av.z * bv.z + av.w * bv.w;
    }
    #pragma unroll
    for (int off = 1; off < 64; off <<= 1) acc += __shfl_xor(acc, off, 64);
    if (lane == 0) M[c * 32 + cp] = acc;
}

// ---------- K1: xh = f16(x), yh = f16(x @ M) ----------
__global__ __launch_bounds__(256) void proj2_kernel(const float* __restrict__ x,
                                                    const float* __restrict__ M,
                                                    f16* __restrict__ yh,
                                                    f16* __restrict__ xh) {
    __shared__ float xs2[32][33];
    const int tid = threadIdx.x;
    const size_t rbase = (size_t)blockIdx.x * 32;
    const int r = tid >> 3, c4 = (tid & 7) * 4;
    float4 xv = *(const float4*)&x[(rbase + r) * CC + c4];
    xs2[r][c4 + 0] = xv.x; xs2[r][c4 + 1] = xv.y;
    xs2[r][c4 + 2] = xv.z; xs2[r][c4 + 3] = xv.w;
    f16x4 xf = {(f16)xv.x, (f16)xv.y, (f16)xv.z, (f16)xv.w};
    *(f16x4*)&xh[(rbase + r) * CC + c4] = xf;
    __syncthreads();
    float a0 = 0.f, a1 = 0.f, a2 = 0.f, a3 = 0.f;
    #pragma unroll
    for (int c = 0; c < 32; c++) {
        const float xr = xs2[r][c];
        const float4 mv = *(const float4*)&M[c * 32 + c4];
        a0 += xr * mv.x; a1 += xr * mv.y; a2 += xr * mv.z; a3 += xr * mv.w;
    }
    f16x4 yf = {(f16)a0, (f16)a1, (f16)a2, (f16)a3};
    *(f16x4*)&yh[(rbase + r) * CC + c4] = yf;
}

// ---------------- K2: per-row max + softmax denom (once per (b, q-tile)) ----------------
// 128 blocks. Two K=32 MFMA sweeps: exact row max, then sum of exp2.
// Outputs: m2g = rowmax * K2E (pre-scaled), lig = 1 / sum.
__global__ __launch_bounds__(256) void ml_kernel(const f16* __restrict__ xh,
                                                 const f16* __restrict__ yh,
                                                 float* __restrict__ m2g,
                                                 float* __restrict__ lig) {
    const int b = blockIdx.x >> 4, qt = blockIdx.x & 15;
    const int tid = threadIdx.x;
    const int lane = tid & 63, wave = tid >> 6;
    const int g = lane >> 4, li = lane & 15;
    const int wr = wave >> 1, wc = wave & 1;
    const int qbase = qt * QB;
    const int qrow0 = qbase + wr * 64;
    const int nst = 2 * qt + 2;

    __shared__ __align__(16) f16 x4[4][64][40];
    __shared__ float mh[2][128];
    __shared__ float lh[2][128];

    const f16* xp = xh + (size_t)b * TT * CC;
    const f16* yp = yh + (size_t)b * TT * CC;

    f16x8 af[4];
    #pragma unroll
    for (int rf = 0; rf < 4; rf++)
        af[rf] = *(const f16x8*)&yp[(size_t)(qbase + wr * 64 + rf * 16 + li) * CC + g * 8];

    const int rr = tid >> 2, c8 = (tid & 3) * 8;

    // sweep 1: exact row max (lane-local)
    float mp[4] = {-3e38f, -3e38f, -3e38f, -3e38f};
    for (int ch = 0; ch * 4 < nst; ch++) {
        __syncthreads();
        #pragma unroll
        for (int j = 0; j < 4; j++) {
            const int st = ch * 4 + j;
            if (st < nst)
                *(f16x8*)&x4[j][rr][c8] = *(const f16x8*)&xp[(size_t)(st * 64 + rr) * CC + c8];
        }
        __syncthreads();
        #pragma unroll
        for (int j = 0; j < 4; j++) {
            const int st = ch * 4 + j;
            if (st < nst) {
                const int sbase = st * 64;
                const bool diag = (sbase + 63) > qrow0;
                #pragma unroll
                for (int sfi = 0; sfi < 2; sfi++) {
                    const f16x8 xa = *(const f16x8*)&x4[j][(2 * wc + sfi) * 16 + li][g * 8];
                    const int sb2 = sbase + (2 * wc + sfi) * 16 + g * 4;
                    #pragma unroll
                    for (int rf = 0; rf < 4; rf++) {
                        f32x4 z = {};
                        f32x4 sc = __builtin_amdgcn_mfma_f32_16x16x32_f16(xa, af[rf], z, 0, 0, 0);
                        const int qg = qbase + wr * 64 + rf * 16 + li;
                        #pragma unroll
                        for (int reg = 0; reg < 4; reg++) {
                            float v = sc[reg];
                            if (diag && (sb2 + reg) > qg) v = -3e38f;
                            mp[rf] = fmaxf(mp[rf], v);
                        }
                    }
                }
            }
        }
    }
    #pragma unroll
    for (int rf = 0; rf < 4; rf++) {
        mp[rf] = fmaxf(mp[rf], __shfl_xor(mp[rf], 16, 64));
        mp[rf] = fmaxf(mp[rf], __shfl_xor(mp[rf], 32, 64));
    }
    if (g == 0) {
        #pragma unroll
        for (int rf = 0; rf < 4; rf++) mh[wc][wr * 64 + rf * 16 + li] = mp[rf];
    }
    __syncthreads();
    float m2[4];
    #pragma unroll
    for (int rf = 0; rf < 4; rf++)
        m2[rf] = fmaxf(mh[0][wr * 64 + rf * 16 + li], mh[1][wr * 64 + rf * 16 + li]) * K2E;

    // sweep 2: sum of exp2
    float lp[4] = {0.f, 0.f, 0.f, 0.f};
    for (int ch = 0; ch * 4 < nst; ch++) {
        __syncthreads();
        #pragma unroll
        for (int j = 0; j < 4; j++) {
            const int st = ch * 4 + j;
            if (st < nst)
                *(f16x8*)&x4[j][rr][c8] = *(const f16x8*)&xp[(size_t)(st * 64 + rr) * CC + c8];
        }
        __syncthreads();
        #pragma unroll
        for (int j = 0; j < 4; j++) {
            const int st = ch * 4 + j;
            if (st < nst) {
                const int sbase = st * 64;
                const bool diag = (sbase + 63) > qrow0;
                #pragma unroll
                for (int sfi = 0; sfi < 2; sfi++) {
                    const f16x8 xa = *(const f16x8*)&x4[j][(2 * wc + sfi) * 16 + li][g * 8];
                    const int sb2 = sbase + (2 * wc + sfi) * 16 + g * 4;
                    #pragma unroll
                    for (int rf = 0; rf < 4; rf++) {
                        f32x4 z = {};
                        f32x4 sc = __builtin_amdgcn_mfma_f32_16x16x32_f16(xa, af[rf], z, 0, 0, 0);
                        const int qg = qbase + wr * 64 + rf * 16 + li;
                        #pragma unroll
                        for (int reg = 0; reg < 4; reg++) {
                            float e = exp2f(fmaf(sc[reg], K2E, -m2[rf]));
                            if (diag && (sb2 + reg) > qg) e = 0.f;
                            lp[rf] += e;
                        }
                    }
                }
            }
        }
    }
    #pragma unroll
    for (int rf = 0; rf < 4; rf++) {
        lp[rf] += __shfl_xor(lp[rf], 16, 64);
        lp[rf] += __shfl_xor(lp[rf], 32, 64);
    }
    if (g == 0) {
        #pragma unroll
        for (int rf = 0; rf < 4; rf++) lh[wc][wr * 64 + rf * 16 + li] = lp[rf];
    }
    __syncthreads();
    if (tid < 128) {
        const float mv = fmaxf(mh[0][tid], mh[1][tid]) * K2E;
        const float lv = lh[0][tid] + lh[1][tid];
        m2g[(size_t)b * TT + qbase + tid] = mv;
        lig[(size_t)b * TT + qbase + tid] = 1.f / lv;
    }
}

// ---------------- K3: single-pass scores + exp + V-projection + PV ----------------
// 256 threads (4 waves, 2x2). m and 1/l precomputed by ml_kernel.
__global__ __launch_bounds__(256, 3) void attn_kernel(
    const f16* __restrict__ xh, const f16* __restrict__ yh,
    const float* __restrict__ Wv, const float* __restrict__ m2g,
    const float* __restrict__ lig, float* __restrict__ out)
{
    const int bid = blockIdx.x;                  // 0..2047
    const int qt  = 15 - (bid >> 7);             // long blocks launch first
    const int b   = (bid >> 4) & 7;
    const int ht  = bid & 15;
    const int tid = threadIdx.x;
    const int lane = tid & 63, wave = tid >> 6;
    const int g = lane >> 4, li = lane & 15;
    const int wr = wave >> 1, wc = wave & 1;
    const int qbase = qt * QB, hbase = ht * HB;
    const int qrow0 = qbase + wr * 64;
    const int nst = 2 * qt + 2;

    __shared__ __align__(16) f16 smem[64 * 40 + 128 * 72 + 128 * 72];  // 42 KB
    f16 (*xs)[40] = (f16(*)[40])smem;
    f16 (*vt)[72] = (f16(*)[72])(smem + 64 * 40);
    f16 (*ps)[72] = (f16(*)[72])(smem + 64 * 40 + 128 * 72);
    __shared__ float mrow[128];
    __shared__ float lrow[128];

    const f16* xp = xh + (size_t)b * TT * CC;
    const f16* yp = yh + (size_t)b * TT * CC;

    if (tid < 128) {
        mrow[tid] = m2g[(size_t)b * TT + qbase + tid];
        lrow[tid] = lig[(size_t)b * TT + qbase + tid];
    }

    f16x8 af[4];
    #pragma unroll
    for (int rf = 0; rf < 4; rf++)
        af[rf] = *(const f16x8*)&yp[(size_t)(qbase + wr * 64 + rf * 16 + li) * CC + g * 8];

    f16x8 wv[4];
    #pragma unroll
    for (int hf = 0; hf < 4; hf++) {
        #pragma unroll
        for (int j = 0; j < 8; j++)
            wv[hf][j] = (f16)Wv[(size_t)(g * 8 + j) * HH + hbase + wc * 64 + hf * 16 + li];
    }

    const int rr = tid >> 2, c8 = (tid & 3) * 8;

    f16x8 xn = *(const f16x8*)&xp[(size_t)rr * CC + c8];   // x(0)
    *(f16x8*)&xs[rr][c8] = xn;
    __syncthreads();

    float m2[4];
    #pragma unroll
    for (int rf = 0; rf < 4; rf++) m2[rf] = mrow[wr * 64 + rf * 16 + li];

    f32x4 o[4][4] = {};
    f16x4 pf0[4], pf1[4];
    f16x4 vf0[4], vf1[4];

    for (int st = 0; st <= nst; st++) {
        const int sbase = st * 64;
        const bool haveQ = (st < nst);
        if (haveQ) {
            if (st + 1 < nst)
                xn = *(const f16x8*)&xp[(size_t)((st + 1) * 64 + rr) * CC + c8];
            const bool diag = (sbase + 63) > qrow0;
            const f16x8 xa0 = *(const f16x8*)&xs[(2 * wc + 0) * 16 + li][g * 8];
            const f16x8 xa1 = *(const f16x8*)&xs[(2 * wc + 1) * 16 + li][g * 8];
            const f16x8 xw0 = *(const f16x8*)&xs[(2 * wr + 0) * 16 + li][g * 8];
            const f16x8 xw1 = *(const f16x8*)&xs[(2 * wr + 1) * 16 + li][g * 8];
            #pragma unroll
            for (int sfi = 0; sfi < 2; sfi++) {
                const f16x8 xa = sfi ? xa1 : xa0;
                const int sb2 = sbase + (2 * wc + sfi) * 16 + g * 4;
                #pragma unroll
                for (int rf = 0; rf < 4; rf++) {
                    f32x4 z = {};
                    f32x4 sc = __builtin_amdgcn_mfma_f32_16x16x32_f16(xa, af[rf], z, 0, 0, 0);
                    const int qg = qbase + wr * 64 + rf * 16 + li;
                    f16x4 pv;
                    #pragma unroll
                    for (int reg = 0; reg < 4; reg++) {
                        float e = exp2f(fmaf(sc[reg], K2E, -m2[rf]));
                        if (diag && (sb2 + reg) > qg) e = 0.f;
                        pv[reg] = (f16)e;
                    }
                    if (sfi == 0) pf0[rf] = pv; else pf1[rf] = pv;
                }
            }
            #pragma unroll
            for (int sfw = 0; sfw < 2; sfw++) {
                const f16x8 xw = sfw ? xw1 : xw0;
                #pragma unroll
                for (int hf = 0; hf < 4; hf++) {
                    f32x4 z = {};
                    f32x4 vc = __builtin_amdgcn_mfma_f32_16x16x32_f16(xw, wv[hf], z, 0, 0, 0);
                    f16x4 vv4;
                    #pragma unroll
                    for (int reg = 0; reg < 4; reg++) vv4[reg] = (f16)vc[reg];
                    if (sfw == 0) vf0[hf] = vv4; else vf1[hf] = vv4;
                }
            }
        }
        if (st > 0) {
            #pragma unroll
            for (int kk = 0; kk < 2; kk++) {
                f16x8 pa[4];
                #pragma unroll
                for (int rf = 0; rf < 4; rf++) {
                    const int prow = wr * 64 + rf * 16 + li;
                    pa[rf] = *(const f16x8*)&ps[prow][(kk * 32 + g * 8) ^ (((prow >> 2) & 3) << 4)];
                }
                #pragma unroll
                for (int hf = 0; hf < 4; hf++) {
                    const int vrow = wc * 64 + hf * 16 + li;
                    const f16x8 vb = *(const f16x8*)&vt[vrow][(kk * 32 + g * 8) ^ (((vrow >> 3) & 3) << 4)];
                    #pragma unroll
                    for (int rf = 0; rf < 4; rf++)
                        o[rf][hf] = __builtin_amdgcn_mfma_f32_16x16x32_f16(pa[rf], vb, o[rf][hf], 0, 0, 0);
                }
            }
        }
        __syncthreads();
        if (haveQ) {
            #pragma unroll
            for (int rf = 0; rf < 4; rf++) {
                const int prow = wr * 64 + rf * 16 + li;
                const int swp = ((prow >> 2) & 3) << 4;
                *(f16x4*)&ps[prow][((2 * wc + 0) * 16 + g * 4) ^ swp] = pf0[rf];
                *(f16x4*)&ps[prow][((2 * wc + 1) * 16 + g * 4) ^ swp] = pf1[rf];
            }
            #pragma unroll
            for (int hf = 0; hf < 4; hf++) {
                const int vrow = wc * 64 + hf * 16 + li;
                const int swv = ((vrow >> 3) & 3) << 4;
                *(f16x4*)&vt[vrow][((2 * wr + 0) * 16 + g * 4) ^ swv] = vf0[hf];
                *(f16x4*)&vt[vrow][((2 * wr + 1) * 16 + g * 4) ^ swv] = vf1[hf];
            }
            if (st + 1 < nst)
                *(f16x8*)&xs[rr][c8] = xn;
            __syncthreads();
        }
    }

    float* op = out + (size_t)b * TT * HH;
    #pragma unroll
    for (int rf = 0; rf < 4; rf++) {
        #pragma unroll
        for (int reg = 0; reg < 4; reg++) {
            const int ql = wr * 64 + rf * 16 + g * 4 + reg;
            const float inv = lrow[ql];
            #pragma unroll
            for (int hf = 0; hf < 4; hf++)
                op[(size_t)(qbase + ql) * HH + hbase + wc * 64 + hf * 16 + li] = o[rf][hf][reg] * inv;
        }
    }
}

extern "C" void kernel_launch(void* const* d_in, const int* in_sizes, int n_in,
                              void* d_out, int out_size, void* d_ws, size_t ws_size,
                              hipStream_t stream) {
    const float* x  = (const float*)d_in[0];
    const float* Wk = (const float*)d_in[1];
    const float* Wq = (const float*)d_in[2];
    const float* Wv = (const float*)d_in[3];
    float* out = (float*)d_out;

    float* Mp = (float*)d_ws;                        // 32x32 fp32
    f16* xh = (f16*)((char*)d_ws + 4096);            // B*T*32 f16 (1 MB)
    f16* yh = xh + (size_t)BB * TT * CC;             // B*T*32 f16 (1 MB)
    float* m2g = (float*)(yh + (size_t)BB * TT * CC);  // B*T f32 (64 KB)
    float* lig = m2g + (size_t)BB * TT;                // B*T f32 (64 KB)

    mk_kernel<<<256, 256, 0, stream>>>(Wq, Wk, Mp);
    proj2_kernel<<<(BB * TT) / 32, 256, 0, stream>>>(x, Mp, yh, xh);
    ml_kernel<<<BB * (TT / QB), 256, 0, stream>>>(xh, yh, m2g, lig);
    attn_kernel<<<BB * (TT / QB) * (HH / HB), 256, 0, stream>>>(xh, yh, Wv, m2g, lig, out);
}